// Round 7
// baseline (304.356 us; speedup 1.0000x reference)
//
#include <hip/hip_runtime.h>

typedef float f4 __attribute__((ext_vector_type(4)));
typedef float f16v __attribute__((ext_vector_type(16)));
typedef _Float16 hf;
typedef __fp16 fp16x2 __attribute__((ext_vector_type(2)));
typedef hf h4 __attribute__((ext_vector_type(4)));
typedef hf h8 __attribute__((ext_vector_type(8)));
typedef unsigned short ushort_t;
typedef unsigned int uint_t;
typedef uint_t u4 __attribute__((ext_vector_type(4)));

#define BATCH 8
#define CH 128
#define NPIX 4096
#define LOG2E 1.4426950408889634f

__device__ inline f16v mfma32h(h8 a, h8 b, f16v c) {
    return __builtin_amdgcn_mfma_f32_32x32x16_f16(a, b, c, 0, 0, 0);
}

__device__ inline uint_t pk2h(float a, float b) {  // pack 2 fp32 -> fp16x2 (RTZ), as u32
    fp16x2 pp = __builtin_amdgcn_cvt_pkrtz(a, b);
    union { fp16x2 v; uint_t u; } cv;
    cv.v = pp;
    return cv.u;
}

typedef __attribute__((address_space(3))) uint_t lds_uint;
typedef __attribute__((address_space(1))) const uint_t global_uint;
__device__ inline void dma16(const void* g, void* l) {
    __builtin_amdgcn_global_load_lds((global_uint*)g, (lds_uint*)l, 16, 0, 0);
}

// ---------------- QKV projection -> fp16 (W read directly, no transpose kernel) ----------------
// Q: [b][n][c] fp16 scaled by log2e;  K: [b][n][c] fp16;  V: [b][c][n] fp16.
// grid: 3*8*64 blocks (64-px chunks), 256 threads; LDS 32 KB -> 5 blocks/CU.
__global__ __launch_bounds__(256) void qkv_kernel(const float* __restrict__ x1,
                                                  const float* __restrict__ x2,
                                                  const float* __restrict__ Wq,
                                                  const float* __restrict__ Wk,
                                                  const float* __restrict__ Wv,
                                                  const float* __restrict__ bq,
                                                  const float* __restrict__ bk,
                                                  const float* __restrict__ bv,
                                                  hf* __restrict__ Qf, hf* __restrict__ Kf,
                                                  hf* __restrict__ Vf) {
    __shared__ __align__(16) float Xs[CH * 64];  // 32 KB

    int bid = blockIdx.x;
    int m = bid >> 9;          // 0..2
    int rem = bid & 511;
    int b = rem & 7;
    int n0 = (rem >> 3) << 6;  // 64-px chunk

    const float* X = ((m == 0) ? x1 : x2) + (size_t)b * CH * NPIX;
    const float* Wm = (m == 0) ? Wq : (m == 1) ? Wk : Wv;  // [o][c], c contiguous
    const float* bias = (m == 0) ? bq : (m == 1) ? bk : bv;

    int tid = threadIdx.x;
#pragma unroll
    for (int r = 0; r < 8; ++r) {
        int idx = r * 256 + tid;
        int c = idx >> 4;
        int p4 = (idx & 15) << 2;
        *(f4*)&Xs[c * 64 + p4] = *(const f4*)&X[(size_t)c * NPIX + n0 + p4];
    }
    __syncthreads();

    int tx = tid & 15;  // pixel quad: 4tx..4tx+3
    int ty = tid >> 4;  // output-channel oct: 8ty..8ty+7

    f4 a[8];
#pragma unroll
    for (int u = 0; u < 8; ++u) a[u] = f4{0.f, 0.f, 0.f, 0.f};

#pragma unroll 2
    for (int c0 = 0; c0 < CH; c0 += 4) {
        f4 xv0 = *(const f4*)&Xs[(c0 + 0) * 64 + 4 * tx];
        f4 xv1 = *(const f4*)&Xs[(c0 + 1) * 64 + 4 * tx];
        f4 xv2 = *(const f4*)&Xs[(c0 + 2) * 64 + 4 * tx];
        f4 xv3 = *(const f4*)&Xs[(c0 + 3) * 64 + 4 * tx];
#pragma unroll
        for (int u = 0; u < 8; ++u) {
            f4 wr = *(const f4*)&Wm[(size_t)(8 * ty + u) * CH + c0];  // L1-broadcast (16 lanes share)
            a[u] += wr[0] * xv0 + wr[1] * xv1 + wr[2] * xv2 + wr[3] * xv3;
        }
    }

    float bb[8];
#pragma unroll
    for (int u = 0; u < 8; ++u) bb[u] = bias[8 * ty + u];

    if (m == 0) {  // Q (scaled by log2e)
#pragma unroll
        for (int p = 0; p < 4; ++p) {
            size_t rowb = ((size_t)b * NPIX + n0 + 4 * tx + p) * CH + 8 * ty;
            h8 hi;
#pragma unroll
            for (int u = 0; u < 8; ++u) hi[u] = (hf)((a[u][p] + bb[u]) * LOG2E);
            *(h8*)&Qf[rowb] = hi;
        }
    } else if (m == 1) {  // K
#pragma unroll
        for (int p = 0; p < 4; ++p) {
            size_t rowb = ((size_t)b * NPIX + n0 + 4 * tx + p) * CH + 8 * ty;
            h8 hi;
#pragma unroll
            for (int u = 0; u < 8; ++u) hi[u] = (hf)(a[u][p] + bb[u]);
            *(h8*)&Kf[rowb] = hi;
        }
    } else {  // V -> [b][c][n]
#pragma unroll
        for (int u = 0; u < 8; ++u) {
            h4 hv;
#pragma unroll
            for (int p = 0; p < 4; ++p) hv[p] = (hf)(a[u][p] + bb[u]);
            *(h4*)&Vf[((size_t)b * CH + 8 * ty + u) * NPIX + n0 + 4 * tx] = hv;
        }
    }
}

// ---------------- fp16 MFMA flash attention, 64q x 32k waves ----------------
// grid: 8*32 = 256 blocks (1/CU), 256 threads = 4 waves:
//   wave w: queries [qh*64, qh*64+64) (qh=w>>1, 2 B-frag groups), keys [kh*32, kh*32+32) (kh=w&1).
// Each K/V A-frag read feeds 2 MFMAs (both q-groups) -> LDS reads per query halved.
// LDS 64 KB: K dbuf @0/8192, V dbuf @16384/24576 (ushort idx). 1 barrier/iter.
__global__ __launch_bounds__(256, 1) void attn_kernel(const hf* __restrict__ Qf,
                                                      const hf* __restrict__ Kf,
                                                      const hf* __restrict__ Vf,
                                                      float* __restrict__ out) {
    __shared__ __align__(16) ushort_t smem[32768];  // 64 KB

    int tid = threadIdx.x;
    int lane = tid & 63;
    int w = tid >> 6;
    int h = lane >> 5;
    int m32 = lane & 31;
    int qh = w >> 1, kh = w & 1;

    int b = blockIdx.x & 7;            // batch <-> XCD for K/V L2 locality
    int i0g = (blockIdx.x >> 3) << 7;  // 128-query tile
    int krow = kh * 32 + m32;

    const hf* Qb = Qf + (size_t)b * NPIX * CH;
    const hf* Kb = Kf + (size_t)b * NPIX * CH;
    const hf* Vb = Vf + (size_t)b * CH * NPIX;

    // Q B-frags for both query groups, in registers for the whole loop
    h8 qf[2][8];
#pragma unroll
    for (int g = 0; g < 2; ++g) {
        size_t row = (size_t)(i0g + qh * 64 + g * 32 + m32) * CH + h * 8;
#pragma unroll
        for (int kc = 0; kc < 8; ++kc) qf[g][kc] = *(const h8*)&Qb[row + kc * 16];
    }

    // DMA source pointers (XOR swizzle folded into global address)
    const hf* pK[4];
    const hf* pV[4];
#pragma unroll
    for (int a = 0; a < 4; ++a) {
        int g = w * 4 + a;
        int rowk = g * 4 + (lane >> 4);
        int lck = (lane & 15) ^ (rowk & 15);
        pK[a] = Kb + (size_t)rowk * CH + lck * 8;
        int rowv = g * 8 + (lane >> 3);
        int lcv = (lane & 7) ^ (rowv & 7);
        pV[a] = Vb + (size_t)rowv * NPIX + lcv * 8;
    }

    // prologue: tile 0 -> buf 0
#pragma unroll
    for (int a = 0; a < 4; ++a) {
        dma16(pK[a], &smem[(w * 4 + a) * 512]);
        dma16(pV[a], &smem[16384 + (w * 4 + a) * 512]);
        pK[a] += 64 * CH;
        pV[a] += 64;
    }

    f16v accO[2][4];
#pragma unroll
    for (int g = 0; g < 2; ++g)
#pragma unroll
        for (int ct = 0; ct < 4; ++ct)
#pragma unroll
            for (int r = 0; r < 16; ++r) accO[g][ct][r] = 0.f;
    float mprev[2] = {-1e30f, -1e30f};
    float lsum[2] = {0.f, 0.f};

    int pc2s[2];
#pragma unroll
    for (int g2 = 0; g2 < 2; ++g2) pc2s[g2] = (kh * 4 + g2 * 2 + h) ^ (m32 & 7);

    __syncthreads();  // tile-0 staged

    for (int t = 0; t < 64; ++t) {
        int cur = t & 1;
        if (t < 63) {
            int nb = 1 - cur;
#pragma unroll
            for (int a = 0; a < 4; ++a) {
                dma16(pK[a], &smem[nb * 8192 + (w * 4 + a) * 512]);
                dma16(pV[a], &smem[16384 + nb * 8192 + (w * 4 + a) * 512]);
                pK[a] += 64 * CH;
                pV[a] += 64;
            }
        }
        const ushort_t* kb = smem + cur * 8192;
        const ushort_t* vb = smem + 16384 + cur * 8192;

        // --- S^T[key][query] = K . Q^T for both q-groups (each A-frag used twice) ---
        f16v acc0, acc1;
#pragma unroll
        for (int r = 0; r < 16; ++r) { acc0[r] = 0.f; acc1[r] = 0.f; }
#pragma unroll
        for (int kc = 0; kc < 8; ++kc) {
            int pA = (kc * 2 + h) ^ (m32 & 15);
            h8 ahi = *(const h8*)&kb[krow * 128 + pA * 8];
            acc0 = mfma32h(ahi, qf[0][kc], acc0);
            acc1 = mfma32h(ahi, qf[1][kc], acc1);
        }

        // --- wave-private online softmax per q-group (base-2 units) ---
        h8 pbp[2][2];
#pragma unroll
        for (int g = 0; g < 2; ++g) {
            f16v& acc = g ? acc1 : acc0;
            float mx[8];
#pragma unroll
            for (int r = 0; r < 8; ++r) mx[r] = fmaxf(acc[r], acc[r + 8]);
#pragma unroll
            for (int r = 0; r < 4; ++r) mx[r] = fmaxf(mx[r], mx[r + 4]);
            float tmax = fmaxf(fmaxf(mx[0], mx[1]), fmaxf(mx[2], mx[3]));
            tmax = fmaxf(tmax, __shfl_xor(tmax, 32));
            if (__any(tmax > mprev[g])) {
                float mnew = fmaxf(mprev[g], tmax);
                float alpha = exp2f(mprev[g] - mnew);
                lsum[g] *= alpha;
#pragma unroll
                for (int ct = 0; ct < 4; ++ct)
#pragma unroll
                    for (int r = 0; r < 16; ++r) accO[g][ct][r] *= alpha;
                mprev[g] = mnew;
            }

            float p[16];
#pragma unroll
            for (int r = 0; r < 16; ++r) p[r] = exp2f(acc[r] - mprev[g]);
            float ps[8];
#pragma unroll
            for (int r = 0; r < 8; ++r) ps[r] = p[r] + p[r + 8];
#pragma unroll
            for (int r = 0; r < 4; ++r) ps[r] += ps[r + 4];
            float psum = (ps[0] + ps[1]) + (ps[2] + ps[3]);
            psum += __shfl_xor(psum, 32);
            lsum[g] += psum;

            // pack P into PV B-frags (lane<->lane^32 exchange)
            uint_t pk[8], rv[8];
#pragma unroll
            for (int t2 = 0; t2 < 8; ++t2) pk[t2] = pk2h(p[2 * t2], p[2 * t2 + 1]);
#pragma unroll
            for (int t2 = 0; t2 < 8; ++t2) rv[t2] = (uint_t)__shfl_xor((int)pk[t2], 32);
#pragma unroll
            for (int g2 = 0; g2 < 2; ++g2) {
                u4 fv;
                fv[0] = h ? rv[g2 * 4 + 2] : pk[g2 * 4 + 0];
                fv[1] = h ? rv[g2 * 4 + 3] : pk[g2 * 4 + 1];
                fv[2] = h ? pk[g2 * 4 + 2] : rv[g2 * 4 + 0];
                fv[3] = h ? pk[g2 * 4 + 3] : rv[g2 * 4 + 1];
                __builtin_memcpy(&pbp[g][g2], &fv, 16);
            }
        }

        // --- O^T[c][q] += V . P, both q-groups share each V A-frag ---
#pragma unroll
        for (int g2 = 0; g2 < 2; ++g2) {
            int pc2 = pc2s[g2];
#pragma unroll
            for (int ct = 0; ct < 4; ++ct) {
                h8 av = *(const h8*)&vb[(ct * 32 + m32) * 64 + pc2 * 8];
                accO[0][ct] = mfma32h(av, pbp[0][g2], accO[0][ct]);
                accO[1][ct] = mfma32h(av, pbp[1][g2], accO[1][ct]);
            }
        }

        __syncthreads();  // drains DMA(t+1); all reads of tile t done
    }

    // --- epilogue: merge key-half waves, store out[b][c][i] ---
    float* scr = (float*)smem;
    if (h == 0) {
#pragma unroll
        for (int g = 0; g < 2; ++g) {
            scr[kh * 128 + qh * 64 + g * 32 + m32] = mprev[g];
            scr[256 + kh * 128 + qh * 64 + g * 32 + m32] = lsum[g];
        }
    }
    __syncthreads();
    float rinv[2];
#pragma unroll
    for (int g = 0; g < 2; ++g) {
        float mo = scr[(1 - kh) * 128 + qh * 64 + g * 32 + m32];
        float lo2 = scr[256 + (1 - kh) * 128 + qh * 64 + g * 32 + m32];
        float mf = fmaxf(mprev[g], mo);
        float fs = exp2f(mprev[g] - mf);
        float fo = exp2f(mo - mf);
        rinv[g] = fs / (fs * lsum[g] + fo * lo2);
    }
    __syncthreads();  // scr reads done before mrg overwrite

    float* mrg = (float*)smem;  // [ch][q_local] 128x128 floats = 64 KB
    if (kh == 1) {
#pragma unroll
        for (int g = 0; g < 2; ++g)
#pragma unroll
            for (int ct = 0; ct < 4; ++ct)
#pragma unroll
                for (int r = 0; r < 16; ++r) {
                    int ch = ct * 32 + (r & 3) + 8 * (r >> 2) + 4 * h;
                    mrg[ch * 128 + qh * 64 + g * 32 + m32] = accO[g][ct][r] * rinv[g];
                }
    }
    __syncthreads();
    if (kh == 0) {
        float* O = out + (size_t)b * CH * NPIX;
#pragma unroll
        for (int g = 0; g < 2; ++g)
#pragma unroll
            for (int ct = 0; ct < 4; ++ct)
#pragma unroll
                for (int r = 0; r < 16; ++r) {
                    int ch = ct * 32 + (r & 3) + 8 * (r >> 2) + 4 * h;
                    int ql = qh * 64 + g * 32 + m32;
                    O[(size_t)ch * NPIX + i0g + ql] =
                        accO[g][ct][r] * rinv[g] + mrg[ch * 128 + ql];
                }
    }
}

extern "C" void kernel_launch(void* const* d_in, const int* in_sizes, int n_in,
                              void* d_out, int out_size, void* d_ws, size_t ws_size,
                              hipStream_t stream) {
    const float* x1 = (const float*)d_in[0];
    const float* x2 = (const float*)d_in[1];
    const float* Wq = (const float*)d_in[2];
    const float* bq = (const float*)d_in[3];
    const float* Wk = (const float*)d_in[4];
    const float* bk = (const float*)d_in[5];
    const float* Wv = (const float*)d_in[6];
    const float* bv = (const float*)d_in[7];
    float* outp = (float*)d_out;

    const size_t N = (size_t)BATCH * NPIX * CH;
    hf* Qf = (hf*)d_ws;
    hf* Kf = Qf + N;
    hf* Vf = Qf + 2 * N;

    qkv_kernel<<<3 * BATCH * (NPIX / 64), 256, 0, stream>>>(x1, x2, Wq, Wk, Wv, bq, bk, bv,
                                                            Qf, Kf, Vf);
    attn_kernel<<<BATCH * (NPIX / 128), 256, 0, stream>>>(Qf, Kf, Vf, outp);
}

// Round 8
// 243.653 us; speedup vs baseline: 1.2491x; 1.2491x over previous
//
#include <hip/hip_runtime.h>

typedef float f4 __attribute__((ext_vector_type(4)));
typedef float f16v __attribute__((ext_vector_type(16)));
typedef _Float16 hf;
typedef __fp16 fp16x2 __attribute__((ext_vector_type(2)));
typedef hf h8 __attribute__((ext_vector_type(8)));
typedef unsigned short ushort_t;
typedef unsigned int uint_t;
typedef uint_t u4 __attribute__((ext_vector_type(4)));

#define BATCH 8
#define CH 128
#define NPIX 4096
#define LOG2E 1.4426950408889634f
#define XSTR 65  // fp32 X tile stride (65 == 1 mod 32 -> conflict-free scalar access)

__device__ inline f16v mfma32h(h8 a, h8 b, f16v c) {
    return __builtin_amdgcn_mfma_f32_32x32x16_f16(a, b, c, 0, 0, 0);
}

__device__ inline uint_t pk2h(float a, float b) {  // pack 2 fp32 -> fp16x2 (RTZ), as u32
    fp16x2 pp = __builtin_amdgcn_cvt_pkrtz(a, b);
    union { fp16x2 v; uint_t u; } cv;
    cv.v = pp;
    return cv.u;
}

typedef __attribute__((address_space(3))) uint_t lds_uint;
typedef __attribute__((address_space(1))) const uint_t global_uint;
__device__ inline void dma16(const void* g, void* l) {
    __builtin_amdgcn_global_load_lds((global_uint*)g, (lds_uint*)l, 16, 0, 0);
}

// ---------------- W prep: WqT,WkT fp16 [c][o] (Wq scaled by log2e); Wv fp16 [o][c] ----------------
__global__ __launch_bounds__(256) void wprep_kernel(const float* __restrict__ Wq,
                                                    const float* __restrict__ Wk,
                                                    const float* __restrict__ Wv,
                                                    hf* __restrict__ WqT, hf* __restrict__ WkT,
                                                    hf* __restrict__ Wv16) {
    int m = blockIdx.x;
    const float* W = (m == 0) ? Wq : (m == 1) ? Wk : Wv;
    float s = (m == 0) ? LOG2E : 1.0f;
    for (int idx = threadIdx.x; idx < CH * CH; idx += 256) {
        int o = idx >> 7, c = idx & 127;
        float v = W[idx] * s;
        if (m == 0) WqT[c * CH + o] = (hf)v;
        else if (m == 1) WkT[c * CH + o] = (hf)v;
        else Wv16[idx] = (hf)v;
    }
}

// ---------------- QKV projection via MFMA (fp16 hi/lo 2-pass) ----------------
// Q: [b][n][c] (log2e-scaled);  K: [b][n][c];  V: [b][c][n].  All fp16.
// grid 3*8*64, 256 thr; LDS 33.3 KB fp32 X tile -> 4 blocks/CU.
__global__ __launch_bounds__(256) void qkv_kernel(const float* __restrict__ x1,
                                                  const float* __restrict__ x2,
                                                  const hf* __restrict__ WqT,
                                                  const hf* __restrict__ WkT,
                                                  const hf* __restrict__ Wv16,
                                                  const float* __restrict__ bq,
                                                  const float* __restrict__ bk,
                                                  const float* __restrict__ bv,
                                                  hf* __restrict__ Qf, hf* __restrict__ Kf,
                                                  hf* __restrict__ Vf) {
    __shared__ __align__(16) float Xs[CH * XSTR];  // X[c][n], padded

    int bid = blockIdx.x;
    int m = bid >> 9;          // 0:Q 1:K 2:V
    int rem = bid & 511;
    int b = rem & 7;
    int n0 = (rem >> 3) << 6;  // 64-px chunk

    const float* X = ((m == 0) ? x1 : x2) + (size_t)b * CH * NPIX;
    const float* bias = (m == 0) ? bq : (m == 1) ? bk : bv;

    int tid = threadIdx.x;
    // stage X fp32 -> LDS [c][XSTR] (coalesced global reads, 2-way-max LDS writes)
#pragma unroll
    for (int r = 0; r < 8; ++r) {
        int c = 16 * r + (tid >> 4);
        int n4 = (tid & 15) << 2;
        f4 v = *(const f4*)&X[(size_t)c * NPIX + n0 + n4];
#pragma unroll
        for (int j = 0; j < 4; ++j) Xs[c * XSTR + n4 + j] = v[j];
    }
    __syncthreads();

    int lane = tid & 63;
    int w = tid >> 6;
    int h = lane >> 5;
    int m32 = lane & 31;
    int o0 = w * 32;  // this wave's 32 output channels

    // W fragments (held in registers for the whole block)
    h8 wf[8];
    if (m == 2) {  // A-operand: Wv[o][c], b128 loads
#pragma unroll
        for (int kc = 0; kc < 8; ++kc)
            wf[kc] = *(const h8*)&Wv16[(size_t)(o0 + m32) * CH + kc * 16 + h * 8];
    } else {  // B-operand: WT[c][o], scalar loads (L1/L2-resident)
        const hf* WT = (m == 0) ? WqT : WkT;
#pragma unroll
        for (int kc = 0; kc < 8; ++kc) {
            h8 t;
#pragma unroll
            for (int j = 0; j < 8; ++j) t[j] = WT[(size_t)(kc * 16 + h * 8 + j) * CH + o0 + m32];
            wf[kc] = t;
        }
    }

    f16v acc[2];
#pragma unroll
    for (int g = 0; g < 2; ++g)
#pragma unroll
        for (int r = 0; r < 16; ++r) acc[g][r] = 0.f;

#pragma unroll
    for (int g = 0; g < 2; ++g) {
        const float* xbase = &Xs[h * 8 * XSTR + g * 32 + m32];
#pragma unroll
        for (int kc = 0; kc < 8; ++kc) {
            // build X hi/lo fp16 fragments from 8 scalar fp32 LDS reads
            h8 xh, xl;
#pragma unroll
            for (int j = 0; j < 8; ++j) {
                float f = xbase[(kc * 16 + j) * XSTR];
                hf hi = (hf)f;
                xh[j] = hi;
                xl[j] = (hf)(f - (float)hi);
            }
            if (m == 2) {  // V: D[o][n] = W . X
                acc[g] = mfma32h(wf[kc], xh, acc[g]);
                acc[g] = mfma32h(wf[kc], xl, acc[g]);
            } else {  // Q/K: D[n][o] = X^T . W^T
                acc[g] = mfma32h(xh, wf[kc], acc[g]);
                acc[g] = mfma32h(xl, wf[kc], acc[g]);
            }
        }
    }

    if (m < 2) {  // D[n][o]: col=o (lane), rows=n; store [b][n][c], lanes coalesced in o
        float bval = bias[o0 + m32] * ((m == 0) ? LOG2E : 1.0f);
        hf* Y = ((m == 0) ? Qf : Kf) + (size_t)b * NPIX * CH;
#pragma unroll
        for (int g = 0; g < 2; ++g)
#pragma unroll
            for (int r = 0; r < 16; ++r) {
                int n = n0 + g * 32 + (r & 3) + 8 * (r >> 2) + 4 * h;
                Y[(size_t)n * CH + o0 + m32] = (hf)(acc[g][r] + bval);
            }
    } else {  // D[o][n]: col=n (lane), rows=o; store [b][c][n], lanes coalesced in n
        hf* Yv = Vf + (size_t)b * CH * NPIX;
#pragma unroll
        for (int g = 0; g < 2; ++g)
#pragma unroll
            for (int r = 0; r < 16; ++r) {
                int o = o0 + (r & 3) + 8 * (r >> 2) + 4 * h;
                Yv[(size_t)o * NPIX + n0 + g * 32 + m32] = (hf)(acc[g][r] + bias[o]);
            }
    }
}

// ---------------- fp16 MFMA flash attention, split-K, 64q x 32k waves ----------------
// grid: 8b * 2ksides * 32qtiles = 512 blocks = 2 blocks/CU. 256 thr (2 qhalves x 2 khalves).
// Each block: 128 queries x 2048 keys (32 iters of 64-key tiles), writes fp16 partial + (m,l).
// LDS 64 KB: K dbuf @0/8192, V dbuf @16384/24576 (ushort idx). 1 barrier/iter.
__global__ __launch_bounds__(256, 2) void attn_kernel(const hf* __restrict__ Qf,
                                                      const hf* __restrict__ Kf,
                                                      const hf* __restrict__ Vf,
                                                      hf* __restrict__ Opart,
                                                      float* __restrict__ Mpart,
                                                      float* __restrict__ Lpart) {
    __shared__ __align__(16) ushort_t smem[32768];  // 64 KB

    int tid = threadIdx.x;
    int lane = tid & 63;
    int w = tid >> 6;
    int h = lane >> 5;
    int m32 = lane & 31;
    int qh = w >> 1, kh = w & 1;

    int idx = blockIdx.x;
    int b = idx & 7;             // batch <-> XCD
    int ks = (idx >> 3) & 1;     // key side
    int qt = idx >> 4;           // query tile (128 q)
    int i0g = qt << 7;
    int k0g = ks << 11;          // 2048-key base
    int krow = kh * 32 + m32;

    const hf* Qb = Qf + (size_t)b * NPIX * CH;
    const hf* Kb = Kf + (size_t)b * NPIX * CH;
    const hf* Vb = Vf + (size_t)b * CH * NPIX;

    // Q B-frags for both query groups, registers for whole loop
    h8 qf[2][8];
#pragma unroll
    for (int g = 0; g < 2; ++g) {
        size_t row = (size_t)(i0g + qh * 64 + g * 32 + m32) * CH + h * 8;
#pragma unroll
        for (int kc = 0; kc < 8; ++kc) qf[g][kc] = *(const h8*)&Qb[row + kc * 16];
    }

    // DMA source pointers (XOR swizzle folded into global address)
    const hf* pK[4];
    const hf* pV[4];
#pragma unroll
    for (int a = 0; a < 4; ++a) {
        int g = w * 4 + a;
        int rowk = g * 4 + (lane >> 4);
        int lck = (lane & 15) ^ (rowk & 15);
        pK[a] = Kb + (size_t)(k0g + rowk) * CH + lck * 8;
        int rowv = g * 8 + (lane >> 3);
        int lcv = (lane & 7) ^ (rowv & 7);
        pV[a] = Vb + (size_t)rowv * NPIX + k0g + lcv * 8;
    }

    // prologue: tile 0 -> buf 0
#pragma unroll
    for (int a = 0; a < 4; ++a) {
        dma16(pK[a], &smem[(w * 4 + a) * 512]);
        dma16(pV[a], &smem[16384 + (w * 4 + a) * 512]);
        pK[a] += 64 * CH;
        pV[a] += 64;
    }

    f16v accO[2][4];
#pragma unroll
    for (int g = 0; g < 2; ++g)
#pragma unroll
        for (int ct = 0; ct < 4; ++ct)
#pragma unroll
            for (int r = 0; r < 16; ++r) accO[g][ct][r] = 0.f;
    float mprev[2] = {-1e30f, -1e30f};
    float lsum[2] = {0.f, 0.f};

    int pc2s[2];
#pragma unroll
    for (int g2 = 0; g2 < 2; ++g2) pc2s[g2] = (kh * 4 + g2 * 2 + h) ^ (m32 & 7);

    __syncthreads();  // tile-0 staged

    for (int t = 0; t < 32; ++t) {
        int cur = t & 1;
        if (t < 31) {
            int nb = 1 - cur;
#pragma unroll
            for (int a = 0; a < 4; ++a) {
                dma16(pK[a], &smem[nb * 8192 + (w * 4 + a) * 512]);
                dma16(pV[a], &smem[16384 + nb * 8192 + (w * 4 + a) * 512]);
                pK[a] += 64 * CH;
                pV[a] += 64;
            }
        }
        const ushort_t* kb = smem + cur * 8192;
        const ushort_t* vb = smem + 16384 + cur * 8192;

        // --- S^T[key][query] = K . Q^T for both q-groups (each A-frag feeds 2 MFMAs) ---
        f16v acc0, acc1;
#pragma unroll
        for (int r = 0; r < 16; ++r) { acc0[r] = 0.f; acc1[r] = 0.f; }
#pragma unroll
        for (int kc = 0; kc < 8; ++kc) {
            int pA = (kc * 2 + h) ^ (m32 & 15);
            h8 ahi = *(const h8*)&kb[krow * 128 + pA * 8];
            acc0 = mfma32h(ahi, qf[0][kc], acc0);
            acc1 = mfma32h(ahi, qf[1][kc], acc1);
        }

        // --- wave-private online softmax per q-group (base-2 units) ---
        h8 pbp[2][2];
#pragma unroll
        for (int g = 0; g < 2; ++g) {
            f16v& acc = g ? acc1 : acc0;
            float m1 = fmaxf(fmaxf(acc[0], acc[1]), fmaxf(acc[2], acc[3]));
            float m2 = fmaxf(fmaxf(acc[4], acc[5]), fmaxf(acc[6], acc[7]));
            float m3 = fmaxf(fmaxf(acc[8], acc[9]), fmaxf(acc[10], acc[11]));
            float m4 = fmaxf(fmaxf(acc[12], acc[13]), fmaxf(acc[14], acc[15]));
            float tmax = fmaxf(fmaxf(m1, m2), fmaxf(m3, m4));
            tmax = fmaxf(tmax, __shfl_xor(tmax, 32));
            if (__any(tmax > mprev[g])) {
                float mnew = fmaxf(mprev[g], tmax);
                float alpha = exp2f(mprev[g] - mnew);
                lsum[g] *= alpha;
#pragma unroll
                for (int ct = 0; ct < 4; ++ct)
#pragma unroll
                    for (int r = 0; r < 16; ++r) accO[g][ct][r] *= alpha;
                mprev[g] = mnew;
            }

            float p[16];
#pragma unroll
            for (int r = 0; r < 16; ++r) p[r] = exp2f(acc[r] - mprev[g]);
            float ps[8];
#pragma unroll
            for (int r = 0; r < 8; ++r) ps[r] = p[r] + p[r + 8];
#pragma unroll
            for (int r = 0; r < 4; ++r) ps[r] += ps[r + 4];
            float psum = (ps[0] + ps[1]) + (ps[2] + ps[3]);
            psum += __shfl_xor(psum, 32);
            lsum[g] += psum;

            uint_t pk[8], rv[8];
#pragma unroll
            for (int t2 = 0; t2 < 8; ++t2) pk[t2] = pk2h(p[2 * t2], p[2 * t2 + 1]);
#pragma unroll
            for (int t2 = 0; t2 < 8; ++t2) rv[t2] = (uint_t)__shfl_xor((int)pk[t2], 32);
#pragma unroll
            for (int g2 = 0; g2 < 2; ++g2) {
                u4 fv;
                fv[0] = h ? rv[g2 * 4 + 2] : pk[g2 * 4 + 0];
                fv[1] = h ? rv[g2 * 4 + 3] : pk[g2 * 4 + 1];
                fv[2] = h ? pk[g2 * 4 + 2] : rv[g2 * 4 + 0];
                fv[3] = h ? pk[g2 * 4 + 3] : rv[g2 * 4 + 1];
                __builtin_memcpy(&pbp[g][g2], &fv, 16);
            }
        }

        // --- O^T[c][q] += V . P; both q-groups share each V A-frag ---
#pragma unroll
        for (int g2 = 0; g2 < 2; ++g2) {
            int pc2 = pc2s[g2];
#pragma unroll
            for (int ct = 0; ct < 4; ++ct) {
                h8 av = *(const h8*)&vb[(ct * 32 + m32) * 64 + pc2 * 8];
                accO[0][ct] = mfma32h(av, pbp[0][g2], accO[0][ct]);
                accO[1][ct] = mfma32h(av, pbp[1][g2], accO[1][ct]);
            }
        }

        __syncthreads();  // drains DMA(t+1); all reads of tile t done
    }

    // --- epilogue: merge the two key-half waves, write fp16 partial + (M,L) ---
    float* scr = (float*)smem;
    if (h == 0) {
#pragma unroll
        for (int g = 0; g < 2; ++g) {
            scr[kh * 128 + qh * 64 + g * 32 + m32] = mprev[g];
            scr[256 + kh * 128 + qh * 64 + g * 32 + m32] = lsum[g];
        }
    }
    __syncthreads();
    float fk[2], Mv[2], Lv[2];
#pragma unroll
    for (int g = 0; g < 2; ++g) {
        float mo = scr[(1 - kh) * 128 + qh * 64 + g * 32 + m32];
        float lo2 = scr[256 + (1 - kh) * 128 + qh * 64 + g * 32 + m32];
        float M = fmaxf(mprev[g], mo);
        fk[g] = exp2f(mprev[g] - M);
        float fo = exp2f(mo - M);
        Mv[g] = M;
        Lv[g] = lsum[g] * fk[g] + lo2 * fo;
    }
    __syncthreads();  // scr consumed; smem reusable as mrg

    float* mrg = (float*)smem;  // [ch][q_local] 128x128 = 64 KB
    if (kh == 1) {
#pragma unroll
        for (int g = 0; g < 2; ++g)
#pragma unroll
            for (int ct = 0; ct < 4; ++ct)
#pragma unroll
                for (int r = 0; r < 16; ++r) {
                    int ch = ct * 32 + (r & 3) + 8 * (r >> 2) + 4 * h;
                    mrg[ch * 128 + qh * 64 + g * 32 + m32] = accO[g][ct][r] * fk[g];
                }
    }
    __syncthreads();
    if (kh == 0) {
        size_t base = (((size_t)ks * 8 + b) * 32 + qt) * 16384;
        size_t mlb = (((size_t)ks * 8 + b) * 32 + qt) * 128;
#pragma unroll
        for (int g = 0; g < 2; ++g) {
            int q = qh * 64 + g * 32 + m32;
#pragma unroll
            for (int ct = 0; ct < 4; ++ct)
#pragma unroll
                for (int r = 0; r < 16; ++r) {
                    int ch = ct * 32 + (r & 3) + 8 * (r >> 2) + 4 * h;
                    Opart[base + ch * 128 + q] = (hf)(accO[g][ct][r] * fk[g] + mrg[ch * 128 + q]);
                }
            if (h == 0) {
                Mpart[mlb + q] = Mv[g];
                Lpart[mlb + q] = Lv[g];
            }
        }
    }
}

// ---------------- combine the two key-side partials ----------------
__global__ __launch_bounds__(256) void combine_kernel(const hf* __restrict__ Opart,
                                                      const float* __restrict__ Mp,
                                                      const float* __restrict__ Lp,
                                                      float* __restrict__ out) {
    int idx = blockIdx.x;
    int b = idx & 7;
    int qt = idx >> 3;
    int tid = threadIdx.x;
    int q = tid & 127;
    int ch0 = (tid >> 7) << 6;

    size_t base0 = (((size_t)b) * 32 + qt) * 16384;
    size_t base1 = ((((size_t)8 + b)) * 32 + qt) * 16384;
    size_t ml0 = (((size_t)b) * 32 + qt) * 128 + q;
    size_t ml1 = ((((size_t)8 + b)) * 32 + qt) * 128 + q;

    float M0 = Mp[ml0], M1 = Mp[ml1];
    float L0 = Lp[ml0], L1 = Lp[ml1];
    float M = fmaxf(M0, M1);
    float w0 = exp2f(M0 - M), w1 = exp2f(M1 - M);
    float rd = 1.0f / (w0 * L0 + w1 * L1);

    float* O = out + (size_t)b * CH * NPIX + ((size_t)qt << 7);
#pragma unroll 4
    for (int c = ch0; c < ch0 + 64; ++c) {
        float o0 = (float)Opart[base0 + c * 128 + q];
        float o1 = (float)Opart[base1 + c * 128 + q];
        O[(size_t)c * NPIX + q] = (w0 * o0 + w1 * o1) * rd;
    }
}

extern "C" void kernel_launch(void* const* d_in, const int* in_sizes, int n_in,
                              void* d_out, int out_size, void* d_ws, size_t ws_size,
                              hipStream_t stream) {
    const float* x1 = (const float*)d_in[0];
    const float* x2 = (const float*)d_in[1];
    const float* Wq = (const float*)d_in[2];
    const float* bq = (const float*)d_in[3];
    const float* Wk = (const float*)d_in[4];
    const float* bk = (const float*)d_in[5];
    const float* Wv = (const float*)d_in[6];
    const float* bv = (const float*)d_in[7];
    float* outp = (float*)d_out;

    const size_t N = (size_t)BATCH * NPIX * CH;  // 4.19M
    hf* Qf = (hf*)d_ws;
    hf* Kf = Qf + N;
    hf* Vf = Qf + 2 * N;
    hf* WqT = Qf + 3 * N;
    hf* WkT = WqT + CH * CH;
    hf* Wv16 = WqT + 2 * CH * CH;
    hf* Opart = WqT + 3 * CH * CH;                       // 2*8*32*16384 hf
    float* Mp = (float*)(Opart + (size_t)2 * 8 * 32 * 16384);
    float* Lp = Mp + (size_t)2 * 8 * 32 * 128;

    wprep_kernel<<<3, 256, 0, stream>>>(Wq, Wk, Wv, WqT, WkT, Wv16);
    qkv_kernel<<<3 * BATCH * (NPIX / 64), 256, 0, stream>>>(x1, x2, WqT, WkT, Wv16,
                                                            bq, bk, bv, Qf, Kf, Vf);
    attn_kernel<<<BATCH * 2 * (NPIX / 128), 256, 0, stream>>>(Qf, Kf, Vf, Opart, Mp, Lp);
    combine_kernel<<<BATCH * (NPIX / 128), 256, 0, stream>>>(Opart, Mp, Lp, outp);
}